// Round 1
// baseline (473.536 us; speedup 1.0000x reference)
//
#include <hip/hip_runtime.h>
#include <hip/hip_bf16.h>

// Problem constants (match reference)
#define RR 3
#define NN 8192
#define BB 4096
#define IN_DIM 256
#define HID 128
#define OUT 64
#define MW (BB / 64)   // 64 mask words per row
#define EPS 1e-5f

// ---------------- BN1 stats: per-column mean/rstd over gathered x ----------------
__global__ __launch_bounds__(256) void bn1_stats_k(const float* __restrict__ feat,
                                                   const int* __restrict__ bn,
                                                   float* __restrict__ m1,
                                                   float* __restrict__ rs1) {
    int c = blockIdx.x;  // 0..IN_DIM-1
    float s = 0.f, q = 0.f;
    for (int i = threadIdx.x; i < BB; i += 256) {
        float v = feat[(size_t)bn[i] * IN_DIM + c];
        s += v; q += v * v;
    }
    int lane = threadIdx.x & 63, wv = threadIdx.x >> 6;
    for (int o = 32; o; o >>= 1) { s += __shfl_down(s, o); q += __shfl_down(q, o); }
    __shared__ float ps[4], pq[4];
    if (lane == 0) { ps[wv] = s; pq[wv] = q; }
    __syncthreads();
    if (threadIdx.x == 0) {
        float S = ps[0] + ps[1] + ps[2] + ps[3];
        float Q = pq[0] + pq[1] + pq[2] + pq[3];
        float m = S / BB;
        float v = Q / BB - m * m;   // biased variance
        m1[c] = m;
        rs1[c] = rsqrtf(v + EPS);
    }
}

// ---------------- xn = BN1(x) ----------------
__global__ __launch_bounds__(256) void xn_norm_k(const float* __restrict__ feat,
                                                 const int* __restrict__ bn,
                                                 const float* __restrict__ m1,
                                                 const float* __restrict__ rs1,
                                                 const float* __restrict__ g1,
                                                 const float* __restrict__ b1,
                                                 float* __restrict__ xn) {
    int i = blockIdx.x, c = threadIdx.x;  // grid BB, block IN_DIM
    float v = feat[(size_t)bn[i] * IN_DIM + c];
    xn[(size_t)i * IN_DIM + c] = (v - m1[c]) * rs1[c] * g1[c] + b1[c];
}

// ---------------- gather adjacency into bitmask + degree ----------------
__global__ __launch_bounds__(256) void build_mask_k(const float* __restrict__ adj,
                                                    const int* __restrict__ bn,
                                                    unsigned long long* __restrict__ mask,
                                                    float* __restrict__ dinv) {
    __shared__ int sbn[BB];  // 16 KB
    for (int t = threadIdx.x; t < BB; t += 256) sbn[t] = bn[t];
    __syncthreads();
    int blk = blockIdx.x;            // r*BB + i
    int r = blk / BB, i = blk - r * BB;
    const float* arow = adj + (size_t)r * NN * NN + (size_t)sbn[i] * NN;
    int lane = threadIdx.x & 63, wv = threadIdx.x >> 6;
    int cnt = 0;
    for (int m = wv * 16; m < wv * 16 + 16; ++m) {   // 64 words / 4 waves
        float v = arow[sbn[m * 64 + lane]];
        unsigned long long bm = __ballot(v != 0.0f);
        if (lane == 0) mask[(size_t)blk * MW + m] = bm;
        cnt += (v != 0.0f) ? 1 : 0;
    }
    for (int o = 32; o; o >>= 1) cnt += __shfl_down(cnt, o);
    __shared__ int pc[4];
    if (lane == 0) pc[wv] = cnt;
    __syncthreads();
    if (threadIdx.x == 0) {
        float deg = (float)(pc[0] + pc[1] + pc[2] + pc[3]) + 1.0f;  // +1 from eye(B)
        dinv[blk] = rsqrtf(deg);
    }
}

// ---------------- layer1: h1 = sigmoid(elu((A_hat @ xn) @ w1)) ----------------
__global__ __launch_bounds__(256) void layer1_k(const float* __restrict__ xn,
                                                const unsigned long long* __restrict__ mask,
                                                const float* __restrict__ dinv,
                                                const float* __restrict__ w1,
                                                float* __restrict__ h1) {
    int blk = blockIdx.x;            // r*BB + i
    int r = blk / BB, i = blk - r * BB;
    int c = threadIdx.x;             // 0..255 (one column of y1)
    const unsigned long long* mrow = mask + (size_t)blk * MW;
    const float* dv = dinv + r * BB;
    float di = dv[i];
    // extra diagonal from +I: A_ii gains +1 -> di*di*xn_i (di factored in at end)
    float acc = di * xn[(size_t)i * IN_DIM + c];
    for (int m = 0; m < MW; ++m) {
        unsigned long long w = mrow[m];
        while (w) {
            int b = __builtin_ctzll(w); w &= w - 1;
            int j = m * 64 + b;
            acc += dv[j] * xn[(size_t)j * IN_DIM + c];
        }
    }
    acc *= di;
    __shared__ float ys[IN_DIM];
    ys[c] = acc;
    __syncthreads();
    if (c < HID) {
        float z = 0.f;
        #pragma unroll 8
        for (int k = 0; k < IN_DIM; ++k) z += ys[k] * w1[k * HID + c];
        float e = z > 0.f ? z : expm1f(z);          // elu
        float h = 1.0f / (1.0f + expf(-e));         // sigmoid
        h1[((size_t)r * BB + i) * HID + c] = h;
    }
}

// ---------------- layer2: h2 = elu((A_hat @ h1) @ w2) ----------------
__global__ __launch_bounds__(128) void layer2_k(const float* __restrict__ h1,
                                                const unsigned long long* __restrict__ mask,
                                                const float* __restrict__ dinv,
                                                const float* __restrict__ w2,
                                                float* __restrict__ h2) {
    int blk = blockIdx.x;
    int r = blk / BB, i = blk - r * BB;
    int c = threadIdx.x;             // 0..127
    const unsigned long long* mrow = mask + (size_t)blk * MW;
    const float* dv = dinv + r * BB;
    const float* h1r = h1 + (size_t)r * BB * HID;
    float di = dv[i];
    float acc = di * h1r[(size_t)i * HID + c];
    for (int m = 0; m < MW; ++m) {
        unsigned long long w = mrow[m];
        while (w) {
            int b = __builtin_ctzll(w); w &= w - 1;
            int j = m * 64 + b;
            acc += dv[j] * h1r[(size_t)j * HID + c];
        }
    }
    acc *= di;
    __shared__ float ys[HID];
    ys[c] = acc;
    __syncthreads();
    if (c < OUT) {
        float z = 0.f;
        #pragma unroll 8
        for (int k = 0; k < HID; ++k) z += ys[k] * w2[k * OUT + c];
        float e = z > 0.f ? z : expm1f(z);          // elu
        h2[((size_t)r * BB + i) * OUT + c] = e;
    }
}

// ---------------- BN2 stats per (relation, column) ----------------
__global__ __launch_bounds__(256) void bn2_stats_k(const float* __restrict__ h2,
                                                   float* __restrict__ m2,
                                                   float* __restrict__ rs2) {
    int ro = blockIdx.x;             // r*OUT + o
    int r = ro / OUT, o = ro - r * OUT;
    float s = 0.f, q = 0.f;
    for (int i = threadIdx.x; i < BB; i += 256) {
        float v = h2[((size_t)r * BB + i) * OUT + o];
        s += v; q += v * v;
    }
    int lane = threadIdx.x & 63, wv = threadIdx.x >> 6;
    for (int off = 32; off; off >>= 1) { s += __shfl_down(s, off); q += __shfl_down(q, off); }
    __shared__ float ps[4], pq[4];
    if (lane == 0) { ps[wv] = s; pq[wv] = q; }
    __syncthreads();
    if (threadIdx.x == 0) {
        float S = ps[0] + ps[1] + ps[2] + ps[3];
        float Q = pq[0] + pq[1] + pq[2] + pq[3];
        float m = S / BB;
        float v = Q / BB - m * m;
        m2[ro] = m;
        rs2[ro] = rsqrtf(v + EPS);
    }
}

// ---------------- finalize: relu(mean_r BN2(h2)) ----------------
__global__ __launch_bounds__(256) void finalize_k(const float* __restrict__ h2,
                                                  const float* __restrict__ m2,
                                                  const float* __restrict__ rs2,
                                                  const float* __restrict__ g2,
                                                  const float* __restrict__ b2,
                                                  float* __restrict__ out) {
    int idx = blockIdx.x * 256 + threadIdx.x;  // i*OUT + o
    if (idx >= BB * OUT) return;
    int o = idx & (OUT - 1);
    float s = 0.f;
    for (int r = 0; r < RR; ++r) {
        float v = h2[(size_t)r * BB * OUT + idx];
        s += (v - m2[r * OUT + o]) * rs2[r * OUT + o] * g2[o] + b2[o];
    }
    s *= (1.0f / RR);
    out[idx] = s > 0.f ? s : 0.f;
}

extern "C" void kernel_launch(void* const* d_in, const int* in_sizes, int n_in,
                              void* d_out, int out_size, void* d_ws, size_t ws_size,
                              hipStream_t stream) {
    const float* feat = (const float*)d_in[0];
    const float* adj  = (const float*)d_in[1];
    const int*   bn   = (const int*)d_in[2];
    const float* w1   = (const float*)d_in[3];
    const float* w2   = (const float*)d_in[4];
    const float* g1   = (const float*)d_in[5];
    const float* b1   = (const float*)d_in[6];
    const float* g2   = (const float*)d_in[7];
    const float* b2   = (const float*)d_in[8];
    float* out = (float*)d_out;

    // workspace layout (bytes); h2 aliases xn (xn dead after layer1)
    char* ws = (char*)d_ws;
    const size_t XN_OFF   = 0;                      // BB*IN_DIM*4   = 4,194,304
    const size_t H2_OFF   = 0;                      // RR*BB*OUT*4   = 3,145,728 (aliases xn)
    const size_t MASK_OFF = 4194304;                // RR*BB*MW*8    = 6,291,456
    const size_t DINV_OFF = MASK_OFF + 6291456;     // RR*BB*4       = 49,152
    const size_t H1_OFF   = DINV_OFF + 49152;       // RR*BB*HID*4   = 6,291,456
    const size_t S1_OFF   = H1_OFF + 6291456;       // 2*IN_DIM*4    = 2,048
    const size_t S2_OFF   = S1_OFF + 2048;          // RR*2*OUT*4    = 1,536
    float* xn   = (float*)(ws + XN_OFF);
    float* h2   = (float*)(ws + H2_OFF);
    unsigned long long* mask = (unsigned long long*)(ws + MASK_OFF);
    float* dinv = (float*)(ws + DINV_OFF);
    float* h1   = (float*)(ws + H1_OFF);
    float* m1   = (float*)(ws + S1_OFF);
    float* rs1  = m1 + IN_DIM;
    float* m2   = (float*)(ws + S2_OFF);
    float* rs2  = m2 + RR * OUT;

    bn1_stats_k<<<IN_DIM, 256, 0, stream>>>(feat, bn, m1, rs1);
    xn_norm_k<<<BB, 256, 0, stream>>>(feat, bn, m1, rs1, g1, b1, xn);
    build_mask_k<<<RR * BB, 256, 0, stream>>>(adj, bn, mask, dinv);
    layer1_k<<<RR * BB, 256, 0, stream>>>(xn, mask, dinv, w1, h1);
    layer2_k<<<RR * BB, 128, 0, stream>>>(h1, mask, dinv, w2, h2);
    bn2_stats_k<<<RR * OUT, 256, 0, stream>>>(h2, m2, rs2);
    finalize_k<<<(BB * OUT + 255) / 256, 256, 0, stream>>>(h2, m2, rs2, g2, b2, out);
}

// Round 2
// 216.075 us; speedup vs baseline: 2.1915x; 2.1915x over previous
//
#include <hip/hip_runtime.h>
#include <hip/hip_bf16.h>

// Problem constants (match reference)
#define RR 3
#define NN 8192
#define BB 4096
#define IN_DIM 256
#define HID 128
#define OUT 64
#define CAPD 128     // padded CSR capacity per row (deg ~ Binom(4096,0.01) ~ 41±6.4; 128 is ~13 sigma)
#define EPS 1e-5f

// ---------------- BN1 stats: per-column mean/rstd over gathered x ----------------
__global__ __launch_bounds__(256) void bn1_stats_k(const float* __restrict__ feat,
                                                   const int* __restrict__ bn,
                                                   float* __restrict__ m1,
                                                   float* __restrict__ rs1) {
    int c = blockIdx.x;  // 0..IN_DIM-1
    float s = 0.f, q = 0.f;
    for (int i = threadIdx.x; i < BB; i += 256) {
        float v = feat[(size_t)bn[i] * IN_DIM + c];
        s += v; q += v * v;
    }
    int lane = threadIdx.x & 63, wv = threadIdx.x >> 6;
    for (int o = 32; o; o >>= 1) { s += __shfl_down(s, o); q += __shfl_down(q, o); }
    __shared__ float ps[4], pq[4];
    if (lane == 0) { ps[wv] = s; pq[wv] = q; }
    __syncthreads();
    if (threadIdx.x == 0) {
        float S = ps[0] + ps[1] + ps[2] + ps[3];
        float Q = pq[0] + pq[1] + pq[2] + pq[3];
        float m = S / BB;
        float v = Q / BB - m * m;   // biased variance
        m1[c] = m;
        rs1[c] = rsqrtf(v + EPS);
    }
}

// ---------------- xn = BN1(x) ----------------
__global__ __launch_bounds__(256) void xn_norm_k(const float* __restrict__ feat,
                                                 const int* __restrict__ bn,
                                                 const float* __restrict__ m1,
                                                 const float* __restrict__ rs1,
                                                 const float* __restrict__ g1,
                                                 const float* __restrict__ b1,
                                                 float* __restrict__ xn) {
    int i = blockIdx.x, c = threadIdx.x;  // grid BB, block IN_DIM
    float v = feat[(size_t)bn[i] * IN_DIM + c];
    xn[(size_t)i * IN_DIM + c] = (v - m1[c]) * rs1[c] * g1[c] + b1[c];
}

// ---------------- build padded CSR from adjacency (coalesced row read + LDS bit-select) ----
__global__ __launch_bounds__(256) void build_csr_k(const float* __restrict__ adj,
                                                   const int* __restrict__ bn,
                                                   unsigned short* __restrict__ cols,
                                                   int* __restrict__ cnt,
                                                   float* __restrict__ dinv) {
    __shared__ int sbn[BB];                 // 16 KB
    __shared__ unsigned char nib[2048];     // 4-bit chunks of the raw row
    __shared__ unsigned int rawb[256];      // full-row bits: 8192 cols -> 256 u32 words
    __shared__ unsigned long long bm_s[64]; // selected-column ballot words
    __shared__ int basep[65];               // exclusive prefix + total
    int tid = threadIdx.x;
    for (int t = tid; t < BB; t += 256) sbn[t] = bn[t];
    int blk = blockIdx.x;                   // r*BB + i
    int r = blk >> 12, i = blk & (BB - 1);
    int node = bn[i];
    // phase A: coalesced read of the full 8192-float adjacency row; compress to bits
    const float4* ar4 = (const float4*)(adj + ((size_t)r * NN + node) * NN);
    #pragma unroll
    for (int ch = 0; ch < 8; ++ch) {
        float4 v = ar4[ch * 256 + tid];     // cols [4*(ch*256+tid), +4)
        nib[ch * 256 + tid] = (unsigned char)((v.x != 0.f) | ((v.y != 0.f) << 1) |
                                              ((v.z != 0.f) << 2) | ((v.w != 0.f) << 3));
    }
    __syncthreads();
    {   // assemble word tid: cols [32*tid, 32*tid+32) from nib[8*tid..8*tid+7]
        unsigned long long x = *(const unsigned long long*)&nib[tid * 8];
        x = (x | (x >> 4))  & 0x00FF00FF00FF00FFull;
        x = (x | (x >> 8))  & 0x0000FFFF0000FFFFull;
        x = (x | (x >> 16));
        rawb[tid] = (unsigned int)x;
    }
    __syncthreads();
    // phase B: select batch columns via LDS bit lookups; ballot into 64-bit words
    int lane = tid & 63, wv = tid >> 6;
    for (int m = wv * 16; m < wv * 16 + 16; ++m) {
        int sel = sbn[m * 64 + lane];
        int bit = (rawb[sel >> 5] >> (sel & 31)) & 1;
        unsigned long long bm = __ballot(bit != 0);
        if (lane == 0) bm_s[m] = bm;
    }
    __syncthreads();
    if (wv == 0) {  // wave-0 exclusive scan over the 64 word popcounts
        int v = (int)__popcll(bm_s[lane]);
        int xs = v;
        for (int o = 1; o < 64; o <<= 1) { int y = __shfl_up(xs, o); if (lane >= o) xs += y; }
        basep[lane] = xs - v;
        if (lane == 63) basep[64] = xs;
    }
    __syncthreads();
    unsigned short* cb = cols + (size_t)blk * CAPD;
    for (int m = wv * 16; m < wv * 16 + 16; ++m) {
        unsigned long long bm = bm_s[m];
        if ((bm >> lane) & 1ull) {
            int p = basep[m] + (int)__popcll(bm & ((1ull << lane) - 1ull));
            if (p < CAPD) cb[p] = (unsigned short)(m * 64 + lane);
        }
    }
    if (tid == 0) {
        int tot = basep[64];
        cnt[blk] = tot < CAPD ? tot : CAPD;
        dinv[blk] = rsqrtf((float)tot + 1.0f);   // +1 from eye(B)
    }
}

// ---------------- fill CSR weights: wts[k] = dinv[r, cols[k]] ----------------
__global__ __launch_bounds__(CAPD) void csr_wts_k(const unsigned short* __restrict__ cols,
                                                  const int* __restrict__ cnt,
                                                  const float* __restrict__ dinv,
                                                  float* __restrict__ wts) {
    int blk = blockIdx.x;
    int r = blk >> 12;
    int t = threadIdx.x;
    if (t < cnt[blk]) {
        int j = cols[(size_t)blk * CAPD + t];
        wts[(size_t)blk * CAPD + t] = dinv[r * BB + j];
    }
}

// ---------------- layer1: h1 = sigmoid(elu((A_hat @ xn) @ w1)) ----------------
__global__ __launch_bounds__(256) void layer1_k(const float* __restrict__ xn,
                                                const unsigned short* __restrict__ cols,
                                                const float* __restrict__ wts,
                                                const int* __restrict__ cnt,
                                                const float* __restrict__ dinv,
                                                const float* __restrict__ w1,
                                                float* __restrict__ h1) {
    int blk = blockIdx.x;               // r*BB + i
    int i = blk & (BB - 1);
    int c = threadIdx.x;                // one column of the aggregated row
    __shared__ unsigned short scl[CAPD];
    __shared__ float swl[CAPD];
    int n = cnt[blk];
    if (c < CAPD) {
        scl[c] = cols[(size_t)blk * CAPD + c];
        swl[c] = wts[(size_t)blk * CAPD + c];
    }
    __syncthreads();
    float di = dinv[blk];
    float acc = di * xn[(size_t)i * IN_DIM + c];      // +I diagonal term
    #pragma unroll 4
    for (int k = 0; k < n; ++k) {
        acc += swl[k] * xn[(size_t)scl[k] * IN_DIM + c];
    }
    acc *= di;
    __shared__ float ys[IN_DIM];
    ys[c] = acc;
    __syncthreads();
    if (c < HID) {
        float z = 0.f;
        #pragma unroll 8
        for (int k = 0; k < IN_DIM; ++k) z += ys[k] * w1[k * HID + c];
        float e = z > 0.f ? z : expm1f(z);            // elu
        float h = 1.0f / (1.0f + expf(-e));           // sigmoid
        h1[(size_t)blk * HID + c] = h;
    }
}

// ---------------- layer2: h2 = elu((A_hat @ h1) @ w2) ----------------
__global__ __launch_bounds__(128) void layer2_k(const float* __restrict__ h1,
                                                const unsigned short* __restrict__ cols,
                                                const float* __restrict__ wts,
                                                const int* __restrict__ cnt,
                                                const float* __restrict__ dinv,
                                                const float* __restrict__ w2,
                                                float* __restrict__ h2) {
    int blk = blockIdx.x;
    int r = blk >> 12, i = blk & (BB - 1);
    int c = threadIdx.x;                // 0..127
    __shared__ unsigned short scl[CAPD];
    __shared__ float swl[CAPD];
    int n = cnt[blk];
    if (c < CAPD) {
        scl[c] = cols[(size_t)blk * CAPD + c];
        swl[c] = wts[(size_t)blk * CAPD + c];
    }
    __syncthreads();
    const float* h1r = h1 + (size_t)r * BB * HID;
    float di = dinv[blk];
    float acc = di * h1r[(size_t)i * HID + c];
    #pragma unroll 4
    for (int k = 0; k < n; ++k) {
        acc += swl[k] * h1r[(size_t)scl[k] * HID + c];
    }
    acc *= di;
    __shared__ float ys[HID];
    ys[c] = acc;
    __syncthreads();
    if (c < OUT) {
        float z = 0.f;
        #pragma unroll 8
        for (int k = 0; k < HID; ++k) z += ys[k] * w2[k * OUT + c];
        float e = z > 0.f ? z : expm1f(z);            // elu
        h2[((size_t)r * BB + i) * OUT + c] = e;
    }
}

// ---------------- BN2 stats per (relation, column) ----------------
__global__ __launch_bounds__(256) void bn2_stats_k(const float* __restrict__ h2,
                                                   float* __restrict__ m2,
                                                   float* __restrict__ rs2) {
    int ro = blockIdx.x;             // r*OUT + o
    int r = ro / OUT, o = ro - r * OUT;
    float s = 0.f, q = 0.f;
    for (int i = threadIdx.x; i < BB; i += 256) {
        float v = h2[((size_t)r * BB + i) * OUT + o];
        s += v; q += v * v;
    }
    int lane = threadIdx.x & 63, wv = threadIdx.x >> 6;
    for (int off = 32; off; off >>= 1) { s += __shfl_down(s, off); q += __shfl_down(q, off); }
    __shared__ float ps[4], pq[4];
    if (lane == 0) { ps[wv] = s; pq[wv] = q; }
    __syncthreads();
    if (threadIdx.x == 0) {
        float S = ps[0] + ps[1] + ps[2] + ps[3];
        float Q = pq[0] + pq[1] + pq[2] + pq[3];
        float m = S / BB;
        float v = Q / BB - m * m;
        m2[ro] = m;
        rs2[ro] = rsqrtf(v + EPS);
    }
}

// ---------------- finalize: relu(mean_r BN2(h2)) ----------------
__global__ __launch_bounds__(256) void finalize_k(const float* __restrict__ h2,
                                                  const float* __restrict__ m2,
                                                  const float* __restrict__ rs2,
                                                  const float* __restrict__ g2,
                                                  const float* __restrict__ b2,
                                                  float* __restrict__ out) {
    int idx = blockIdx.x * 256 + threadIdx.x;  // i*OUT + o
    if (idx >= BB * OUT) return;
    int o = idx & (OUT - 1);
    float s = 0.f;
    for (int r = 0; r < RR; ++r) {
        float v = h2[(size_t)r * BB * OUT + idx];
        s += (v - m2[r * OUT + o]) * rs2[r * OUT + o] * g2[o] + b2[o];
    }
    s *= (1.0f / RR);
    out[idx] = s > 0.f ? s : 0.f;
}

extern "C" void kernel_launch(void* const* d_in, const int* in_sizes, int n_in,
                              void* d_out, int out_size, void* d_ws, size_t ws_size,
                              hipStream_t stream) {
    const float* feat = (const float*)d_in[0];
    const float* adj  = (const float*)d_in[1];
    const int*   bn   = (const int*)d_in[2];
    const float* w1   = (const float*)d_in[3];
    const float* w2   = (const float*)d_in[4];
    const float* g1   = (const float*)d_in[5];
    const float* b1   = (const float*)d_in[6];
    const float* g2   = (const float*)d_in[7];
    const float* b2   = (const float*)d_in[8];
    float* out = (float*)d_out;

    // workspace layout (bytes); h2 aliases xn (xn dead after layer1)
    char* ws = (char*)d_ws;
    const size_t XN_OFF   = 0;                        // BB*IN_DIM*4        = 4,194,304
    const size_t H2_OFF   = 0;                        // RR*BB*OUT*4        = 3,145,728 (aliases xn)
    const size_t COLS_OFF = 4194304;                  // RR*BB*CAPD*2       = 3,145,728
    const size_t WTS_OFF  = COLS_OFF + 3145728;       // RR*BB*CAPD*4       = 6,291,456
    const size_t CNT_OFF  = WTS_OFF + 6291456;        // RR*BB*4            = 49,152
    const size_t DINV_OFF = CNT_OFF + 49152;          // RR*BB*4            = 49,152
    const size_t H1_OFF   = DINV_OFF + 49152;         // RR*BB*HID*4        = 6,291,456
    const size_t S1_OFF   = H1_OFF + 6291456;         // 2*IN_DIM*4         = 2,048
    const size_t S2_OFF   = S1_OFF + 2048;            // RR*2*OUT*4         = 1,536
    float* xn   = (float*)(ws + XN_OFF);
    float* h2   = (float*)(ws + H2_OFF);
    unsigned short* cols = (unsigned short*)(ws + COLS_OFF);
    float* wts  = (float*)(ws + WTS_OFF);
    int*   cnt  = (int*)(ws + CNT_OFF);
    float* dinv = (float*)(ws + DINV_OFF);
    float* h1   = (float*)(ws + H1_OFF);
    float* m1   = (float*)(ws + S1_OFF);
    float* rs1  = m1 + IN_DIM;
    float* m2   = (float*)(ws + S2_OFF);
    float* rs2  = m2 + RR * OUT;

    bn1_stats_k<<<IN_DIM, 256, 0, stream>>>(feat, bn, m1, rs1);
    xn_norm_k<<<BB, 256, 0, stream>>>(feat, bn, m1, rs1, g1, b1, xn);
    build_csr_k<<<RR * BB, 256, 0, stream>>>(adj, bn, cols, cnt, dinv);
    csr_wts_k<<<RR * BB, CAPD, 0, stream>>>(cols, cnt, dinv, wts);
    layer1_k<<<RR * BB, 256, 0, stream>>>(xn, cols, wts, cnt, dinv, w1, h1);
    layer2_k<<<RR * BB, 128, 0, stream>>>(h1, cols, wts, cnt, dinv, w2, h2);
    bn2_stats_k<<<RR * OUT, 256, 0, stream>>>(h2, m2, rs2);
    finalize_k<<<(BB * OUT + 255) / 256, 256, 0, stream>>>(h2, m2, rs2, g2, b2, out);
}

// Round 3
// 176.480 us; speedup vs baseline: 2.6832x; 1.2244x over previous
//
#include <hip/hip_runtime.h>
#include <hip/hip_bf16.h>

// Problem constants (match reference)
#define RR 3
#define NN 8192
#define BB 4096
#define IN_DIM 256
#define HID 128
#define OUT 64
#define CAPD 128     // padded list capacity (unique nbr nodes ~ Binom(3224,0.01) ~ 32±5.7)
#define EPS 1e-5f
#define MWN (NN / 64)   // 128 mask words over node space

// ---- prep: multiplicity, membership bitmap, rank compaction, pos->slot ----
__global__ __launch_bounds__(1024) void prep_k(const int* __restrict__ bn,
                                               unsigned long long* __restrict__ memb,
                                               unsigned short* __restrict__ rankg,
                                               unsigned short* __restrict__ nodeof,
                                               float* __restrict__ multf,
                                               int* __restrict__ Ucnt,
                                               unsigned short* __restrict__ pos2slot) {
    __shared__ int smult[NN];                 // 32 KB
    __shared__ unsigned short srank[NN];      // 16 KB
    __shared__ unsigned long long smemb[MWN]; // 1 KB
    __shared__ int sbase[MWN + 1];
    int t = threadIdx.x;
    for (int u = t; u < NN; u += 1024) smult[u] = 0;
    __syncthreads();
    for (int i = t; i < BB; i += 1024) atomicAdd(&smult[bn[i]], 1);
    __syncthreads();
    if (t < MWN) {
        unsigned long long w = 0;
        for (int b = 0; b < 64; ++b) if (smult[t * 64 + b]) w |= (1ull << b);
        smemb[t] = w;
        memb[t] = w;
    }
    __syncthreads();
    if (t == 0) {
        int acc = 0;
        for (int m = 0; m < MWN; ++m) { sbase[m] = acc; acc += (int)__popcll(smemb[m]); }
        sbase[MWN] = acc;
        *Ucnt = acc;
    }
    __syncthreads();
    if (t < MWN) {
        unsigned long long w = smemb[t];
        int p = sbase[t];
        while (w) {
            int b = __builtin_ctzll(w); w &= w - 1;
            int u = t * 64 + b;
            srank[u] = (unsigned short)p;
            rankg[u] = (unsigned short)p;
            nodeof[p] = (unsigned short)u;
            multf[p]  = (float)smult[u];
            ++p;
        }
    }
    __syncthreads();
    for (int i = t; i < BB; i += 1024) pos2slot[i] = srank[bn[i]];
}

// ---- BN1 stats: per-column mean/rstd over gathered x (positions) ----
__global__ __launch_bounds__(256) void bn1_stats_k(const float* __restrict__ feat,
                                                   const int* __restrict__ bn,
                                                   float* __restrict__ m1,
                                                   float* __restrict__ rs1) {
    int c = blockIdx.x;  // 0..IN_DIM-1
    float s = 0.f, q = 0.f;
    for (int i = threadIdx.x; i < BB; i += 256) {
        float v = feat[(size_t)bn[i] * IN_DIM + c];
        s += v; q += v * v;
    }
    int lane = threadIdx.x & 63, wv = threadIdx.x >> 6;
    for (int o = 32; o; o >>= 1) { s += __shfl_down(s, o); q += __shfl_down(q, o); }
    __shared__ float ps[4], pq[4];
    if (lane == 0) { ps[wv] = s; pq[wv] = q; }
    __syncthreads();
    if (threadIdx.x == 0) {
        float S = ps[0] + ps[1] + ps[2] + ps[3];
        float Q = pq[0] + pq[1] + pq[2] + pq[3];
        float m = S / BB;
        float v = Q / BB - m * m;   // biased variance
        m1[c] = m;
        rs1[c] = rsqrtf(v + EPS);
    }
}

// ---- xn per unique node slot: xn_c[s] = BN1(feat[nodeof[s]]) ----
__global__ __launch_bounds__(256) void xn_c_k(const float* __restrict__ feat,
                                              const unsigned short* __restrict__ nodeof,
                                              const int* __restrict__ Ucnt,
                                              const float* __restrict__ m1,
                                              const float* __restrict__ rs1,
                                              const float* __restrict__ g1,
                                              const float* __restrict__ b1,
                                              float* __restrict__ xn_c) {
    int s = blockIdx.x;
    if (s >= *Ucnt) return;
    int u = nodeof[s];
    int c = threadIdx.x;
    float v = feat[(size_t)u * IN_DIM + c];
    xn_c[(size_t)s * IN_DIM + c] = (v - m1[c]) * rs1[c] * g1[c] + b1[c];
}

// ---- build per (r, slot): coalesced row read -> bits -> AND membership -> list ----
__global__ __launch_bounds__(256) void build_k(const float* __restrict__ adj,
                                               const unsigned short* __restrict__ nodeof,
                                               const int* __restrict__ Ucnt,
                                               const unsigned long long* __restrict__ memb,
                                               const unsigned short* __restrict__ rankg,
                                               const float* __restrict__ multf,
                                               unsigned short* __restrict__ cols,
                                               int* __restrict__ cnt,
                                               float* __restrict__ dinv) {
    int blk = blockIdx.x;                   // r*4096 + s
    int r = blk >> 12, s = blk & (BB - 1);
    if (s >= *Ucnt) return;
    int u = nodeof[s];
    __shared__ unsigned char nib[2048];
    __shared__ unsigned int rawb[256];
    __shared__ unsigned long long sel[MWN];
    __shared__ int sbase[MWN + 1];
    __shared__ float pdeg[4];
    int t = threadIdx.x;
    // phase A: coalesced read of the 8192-float adjacency row; compress to bits
    const float4* ar4 = (const float4*)(adj + ((size_t)r * NN + u) * NN);
    #pragma unroll
    for (int ch = 0; ch < 8; ++ch) {
        float4 v = ar4[ch * 256 + t];
        nib[ch * 256 + t] = (unsigned char)((v.x != 0.f) | ((v.y != 0.f) << 1) |
                                            ((v.z != 0.f) << 2) | ((v.w != 0.f) << 3));
    }
    __syncthreads();
    {   // assemble u32 word t: cols [32t, 32t+32)
        unsigned long long x = *(const unsigned long long*)&nib[t * 8];
        x = (x | (x >> 4))  & 0x00FF00FF00FF00FFull;
        x = (x | (x >> 8))  & 0x0000FFFF0000FFFFull;
        x = (x | (x >> 16));
        rawb[t] = (unsigned int)x;
    }
    __syncthreads();
    // phase B: select member columns = raw & memb
    if (t < MWN) {
        unsigned long long w = ((unsigned long long)rawb[2 * t + 1] << 32) | rawb[2 * t];
        sel[t] = w & memb[t];
    }
    __syncthreads();
    // phase C: exclusive scan of word popcounts (wave 0, 2 words/lane)
    if (t < 64) {
        int p0 = (int)__popcll(sel[2 * t]);
        int p1 = (int)__popcll(sel[2 * t + 1]);
        int x = p0 + p1, xs = x;
        for (int o = 1; o < 64; o <<= 1) { int y = __shfl_up(xs, o); if (t >= o) xs += y; }
        sbase[2 * t]     = xs - x;
        sbase[2 * t + 1] = xs - p1;
        if (t == 63) sbase[MWN] = xs;
    }
    __syncthreads();
    // phase D: emit slot list + multiplicity-weighted degree
    float wdeg = 0.f;
    if (t < MWN) {
        unsigned long long w = sel[t];
        int p = sbase[t];
        unsigned short* cb = cols + (size_t)blk * CAPD;
        while (w) {
            int b = __builtin_ctzll(w); w &= w - 1;
            int v = t * 64 + b;
            int rv = rankg[v];
            if (p < CAPD) cb[p] = (unsigned short)rv;
            wdeg += multf[rv];
            ++p;
        }
    }
    int lane = t & 63, wv = t >> 6;
    for (int o = 32; o; o >>= 1) wdeg += __shfl_down(wdeg, o);
    if (lane == 0) pdeg[wv] = wdeg;
    __syncthreads();
    if (t == 0) {
        int tot = sbase[MWN];
        cnt[blk] = tot < CAPD ? tot : CAPD;
        dinv[blk] = rsqrtf(pdeg[0] + pdeg[1] + pdeg[2] + pdeg[3] + 1.0f);  // +1 from eye
    }
}

// ---- layer1 per (r, slot): h1 = sigmoid(elu((A_hat @ xn) @ w1)) ----
__global__ __launch_bounds__(256) void layer1_k(const float* __restrict__ xn_c,
                                                const unsigned short* __restrict__ cols,
                                                const int* __restrict__ cnt,
                                                const float* __restrict__ dinv,
                                                const float* __restrict__ multf,
                                                const int* __restrict__ Ucnt,
                                                const float* __restrict__ w1,
                                                float* __restrict__ h1) {
    int blk = blockIdx.x;                // r*4096 + s
    int r = blk >> 12, s = blk & (BB - 1);
    if (s >= *Ucnt) return;
    int c = threadIdx.x;
    __shared__ unsigned short scl[CAPD];
    __shared__ float swl[CAPD];
    int n = cnt[blk];
    if (c < n) {
        int sl = cols[(size_t)blk * CAPD + c];
        scl[c] = (unsigned short)sl;
        swl[c] = multf[sl] * dinv[(r << 12) + sl];
    }
    __syncthreads();
    float di = dinv[blk];
    float acc = di * xn_c[(size_t)s * IN_DIM + c];      // eye diagonal term
    #pragma unroll 4
    for (int k = 0; k < n; ++k) {
        acc += swl[k] * xn_c[(size_t)scl[k] * IN_DIM + c];
    }
    acc *= di;
    __shared__ float ys[IN_DIM];
    ys[c] = acc;
    __syncthreads();
    if (c < HID) {
        float z = 0.f;
        #pragma unroll 8
        for (int k = 0; k < IN_DIM; ++k) z += ys[k] * w1[k * HID + c];
        float e = z > 0.f ? z : expm1f(z);              // elu
        float h = 1.0f / (1.0f + expf(-e));             // sigmoid
        h1[(size_t)blk * HID + c] = h;
    }
}

// ---- layer2 per (r, slot): h2 = elu((A_hat @ h1) @ w2) ----
__global__ __launch_bounds__(128) void layer2_k(const float* __restrict__ h1,
                                                const unsigned short* __restrict__ cols,
                                                const int* __restrict__ cnt,
                                                const float* __restrict__ dinv,
                                                const float* __restrict__ multf,
                                                const int* __restrict__ Ucnt,
                                                const float* __restrict__ w2,
                                                float* __restrict__ h2) {
    int blk = blockIdx.x;
    int r = blk >> 12, s = blk & (BB - 1);
    if (s >= *Ucnt) return;
    int c = threadIdx.x;                 // 0..127
    __shared__ unsigned short scl[CAPD];
    __shared__ float swl[CAPD];
    int n = cnt[blk];
    if (c < n) {
        int sl = cols[(size_t)blk * CAPD + c];
        scl[c] = (unsigned short)sl;
        swl[c] = multf[sl] * dinv[(r << 12) + sl];
    }
    __syncthreads();
    const float* h1r = h1 + ((size_t)r << 12) * HID;
    float di = dinv[blk];
    float acc = di * h1r[(size_t)s * HID + c];
    #pragma unroll 4
    for (int k = 0; k < n; ++k) {
        acc += swl[k] * h1r[(size_t)scl[k] * HID + c];
    }
    acc *= di;
    __shared__ float ys[HID];
    ys[c] = acc;
    __syncthreads();
    if (c < OUT) {
        float z = 0.f;
        #pragma unroll 8
        for (int k = 0; k < HID; ++k) z += ys[k] * w2[k * OUT + c];
        float e = z > 0.f ? z : expm1f(z);              // elu
        h2[(size_t)blk * OUT + c] = e;
    }
}

// ---- BN2 stats per (relation, column): multiplicity-weighted over slots ----
__global__ __launch_bounds__(256) void bn2_stats_k(const float* __restrict__ h2,
                                                   const float* __restrict__ multf,
                                                   const int* __restrict__ Ucnt,
                                                   float* __restrict__ m2,
                                                   float* __restrict__ rs2) {
    int ro = blockIdx.x;             // r*OUT + o
    int r = ro >> 6, o = ro & (OUT - 1);
    int U = *Ucnt;
    float s = 0.f, q = 0.f;
    for (int sl = threadIdx.x; sl < U; sl += 256) {
        float m = multf[sl];
        float v = h2[(size_t)((r << 12) + sl) * OUT + o];
        s += m * v; q += m * v * v;
    }
    int lane = threadIdx.x & 63, wv = threadIdx.x >> 6;
    for (int off = 32; off; off >>= 1) { s += __shfl_down(s, off); q += __shfl_down(q, off); }
    __shared__ float ps[4], pq[4];
    if (lane == 0) { ps[wv] = s; pq[wv] = q; }
    __syncthreads();
    if (threadIdx.x == 0) {
        float S = ps[0] + ps[1] + ps[2] + ps[3];
        float Q = pq[0] + pq[1] + pq[2] + pq[3];
        float m = S / BB;                 // sum of mult == BB positions
        float v = Q / BB - m * m;
        m2[ro] = m;
        rs2[ro] = rsqrtf(v + EPS);
    }
}

// ---- finalize: out[i] = relu(mean_r BN2(h2[r, slot(i)])) ----
__global__ __launch_bounds__(256) void finalize_k(const float* __restrict__ h2,
                                                  const unsigned short* __restrict__ pos2slot,
                                                  const float* __restrict__ m2,
                                                  const float* __restrict__ rs2,
                                                  const float* __restrict__ g2,
                                                  const float* __restrict__ b2,
                                                  float* __restrict__ out) {
    int idx = blockIdx.x * 256 + threadIdx.x;  // i*OUT + o
    if (idx >= BB * OUT) return;
    int i = idx >> 6, o = idx & (OUT - 1);
    int sl = pos2slot[i];
    float s = 0.f;
    for (int r = 0; r < RR; ++r) {
        float v = h2[(size_t)((r << 12) + sl) * OUT + o];
        s += (v - m2[r * OUT + o]) * rs2[r * OUT + o] * g2[o] + b2[o];
    }
    s *= (1.0f / RR);
    out[idx] = s > 0.f ? s : 0.f;
}

extern "C" void kernel_launch(void* const* d_in, const int* in_sizes, int n_in,
                              void* d_out, int out_size, void* d_ws, size_t ws_size,
                              hipStream_t stream) {
    const float* feat = (const float*)d_in[0];
    const float* adj  = (const float*)d_in[1];
    const int*   bn   = (const int*)d_in[2];
    const float* w1   = (const float*)d_in[3];
    const float* w2   = (const float*)d_in[4];
    const float* g1   = (const float*)d_in[5];
    const float* b1   = (const float*)d_in[6];
    const float* g2   = (const float*)d_in[7];
    const float* b2   = (const float*)d_in[8];
    float* out = (float*)d_out;

    // workspace layout (256-aligned offsets)
    char* ws = (char*)d_ws;
    size_t off = 0;
    auto alloc = [&](size_t bytes) { size_t o = off; off += (bytes + 255) & ~(size_t)255; return o; };
    unsigned long long* memb = (unsigned long long*)(ws + alloc(MWN * 8));      // 1 KB
    unsigned short* rankg    = (unsigned short*)(ws + alloc(NN * 2));           // 16 KB
    unsigned short* nodeof   = (unsigned short*)(ws + alloc(BB * 2));           // 8 KB
    float* multf             = (float*)(ws + alloc(BB * 4));                    // 16 KB
    int* Ucnt                = (int*)(ws + alloc(4));
    unsigned short* pos2slot = (unsigned short*)(ws + alloc(BB * 2));           // 8 KB
    float* m1                = (float*)(ws + alloc(IN_DIM * 4));
    float* rs1               = (float*)(ws + alloc(IN_DIM * 4));
    float* m2                = (float*)(ws + alloc(RR * OUT * 4));
    float* rs2               = (float*)(ws + alloc(RR * OUT * 4));
    float* xn_c              = (float*)(ws + alloc((size_t)BB * IN_DIM * 4));   // 4 MB
    unsigned short* cols     = (unsigned short*)(ws + alloc((size_t)RR * BB * CAPD * 2)); // 3.1 MB
    int* cnt                 = (int*)(ws + alloc((size_t)RR * BB * 4));         // 48 KB
    float* dinv              = (float*)(ws + alloc((size_t)RR * BB * 4));       // 48 KB
    float* h1                = (float*)(ws + alloc((size_t)RR * BB * HID * 4)); // 6.3 MB
    float* h2                = (float*)(ws + alloc((size_t)RR * BB * OUT * 4)); // 3.1 MB

    prep_k<<<1, 1024, 0, stream>>>(bn, memb, rankg, nodeof, multf, Ucnt, pos2slot);
    bn1_stats_k<<<IN_DIM, 256, 0, stream>>>(feat, bn, m1, rs1);
    xn_c_k<<<BB, 256, 0, stream>>>(feat, nodeof, Ucnt, m1, rs1, g1, b1, xn_c);
    build_k<<<RR * BB, 256, 0, stream>>>(adj, nodeof, Ucnt, memb, rankg, multf, cols, cnt, dinv);
    layer1_k<<<RR * BB, 256, 0, stream>>>(xn_c, cols, cnt, dinv, multf, Ucnt, w1, h1);
    layer2_k<<<RR * BB, 128, 0, stream>>>(h1, cols, cnt, dinv, multf, Ucnt, w2, h2);
    bn2_stats_k<<<RR * OUT, 256, 0, stream>>>(h2, multf, Ucnt, m2, rs2);
    finalize_k<<<(BB * OUT + 255) / 256, 256, 0, stream>>>(h2, pos2slot, m2, rs2, g2, b2, out);
}